// Round 3
// baseline (204.782 us; speedup 1.0000x reference)
//
#include <hip/hip_runtime.h>
#include <math.h>

#define IN_DIM   128
#define OUT_DIM  128
#define N_NEIGH  32
#define BATCH    8192
#define B_TILE   8

// Fully fused: per block, (a) fold W_w/W_b/u into v1,v2,c (redundant across
// blocks; W_w is 64KB and L2/L3-resident), (b) stream B_TILE batch elements'
// 33 rows, dot against v2/v1, (c) softmax over the 32 neighbors, write.
__global__ __launch_bounds__(256) void gat_fused(const float* __restrict__ ai_sq,
                                                 const float* __restrict__ ai_sn,
                                                 const float* __restrict__ W_w,
                                                 const float* __restrict__ W_b,
                                                 const float* __restrict__ u,
                                                 float* __restrict__ out) {
    const int tid = threadIdx.x;
    const int b0  = blockIdx.x * B_TILE;

    __shared__ float sv1[IN_DIM];
    __shared__ float sv2[IN_DIM];
    __shared__ float p1[2][IN_DIM];
    __shared__ float p2[2][IN_DIM];
    __shared__ float sc;
    __shared__ float t[33][B_TILE + 1];   // +1 pad: softmax phase bank spread

    // ---- prep: v1[i]=sum_o W_w[o,i]u[o], v2[i]=sum_o W_w[o,i]u[128+o] ----
    {
        const int i = tid & 127;
        const int h = tid >> 7;          // 0..1 : split the o-range
        float a1 = 0.f, a2 = 0.f;
        #pragma unroll
        for (int oo = 0; oo < 64; ++oo) {
            const int o = h * 64 + oo;   // wave-uniform -> u[] scalarizes
            const float w = W_w[o * IN_DIM + i];   // coalesced across i
            a1 = fmaf(w, u[o], a1);
            a2 = fmaf(w, u[OUT_DIM + o], a2);
        }
        p1[h][i] = a1;
        p2[h][i] = a2;
        if (tid < 64) {   // c = sum_k W_b[k]*(u[k]+u[128+k]), wave 0
            float s = W_b[tid]       * (u[tid]      + u[OUT_DIM + tid]) +
                      W_b[tid + 64]  * (u[tid + 64] + u[OUT_DIM + tid + 64]);
            #pragma unroll
            for (int m = 32; m > 0; m >>= 1) s += __shfl_xor(s, m);
            if (tid == 0) sc = s;
        }
        __syncthreads();
        if (h == 0) {
            sv1[i] = p1[0][i] + p1[1][i];
            sv2[i] = p2[0][i] + p2[1][i];
        }
        __syncthreads();
    }

    const int wave = tid >> 6;       // 0..3
    const int lane = tid & 63;
    const int c    = lane & 31;      // float4 chunk within a 128-float row
    const int hb   = lane >> 5;      // which of the 2 rows in a 1KB load

    const float4 v1c = ((const float4*)sv1)[c];
    const float4 v2c = ((const float4*)sv2)[c];
    const float  cc  = sc;

    // ---- stream: 32 neighbor rows + 1 sq row per batch element ----
    for (int r = wave; r < 33; r += 4) {
        const float* base = (r < 32)
            ? (ai_sn + ((size_t)r * BATCH + b0) * IN_DIM)
            : (ai_sq + (size_t)b0 * IN_DIM);
        const float4 vv = (r < 32) ? v2c : v1c;
        #pragma unroll
        for (int k = 0; k < B_TILE / 2; ++k) {
            const int bl = k * 2 + hb;
            float4 x = ((const float4*)(base + (size_t)bl * IN_DIM))[c];
            float p = x.x * vv.x + x.y * vv.y + x.z * vv.z + x.w * vv.w;
            #pragma unroll
            for (int m = 16; m > 0; m >>= 1) p += __shfl_xor(p, m);
            if (c == 0) t[r][bl] = p;
        }
    }
    __syncthreads();

    // ---- softmax over n: half-wave per batch element ----
    const int n  = tid & 31;
    const int bl = tid >> 5;
    float mult = t[n][bl] + t[32][bl] + cc;
    float l = mult > 0.f ? mult : 0.01f * mult;
    float mx = l;
    #pragma unroll
    for (int m = 16; m > 0; m >>= 1) mx = fmaxf(mx, __shfl_xor(mx, m));
    float e = expf(l - mx);
    float s = e;
    #pragma unroll
    for (int m = 16; m > 0; m >>= 1) s += __shfl_xor(s, m);
    float res = e / s;
    __syncthreads();
    t[n][bl] = res;
    __syncthreads();

    // transpose out of LDS for 32B-contiguous writes per 8 lanes
    const int nn = tid >> 3;
    const int bb = tid & 7;
    out[(size_t)nn * BATCH + b0 + bb] = t[nn][bb];
}

extern "C" void kernel_launch(void* const* d_in, const int* in_sizes, int n_in,
                              void* d_out, int out_size, void* d_ws, size_t ws_size,
                              hipStream_t stream) {
    const float* ai_sq = (const float*)d_in[0];  // (8192, 128)
    const float* ai_sn = (const float*)d_in[1];  // (32, 8192, 128)
    const float* W_w   = (const float*)d_in[2];  // (128, 128)
    const float* W_b   = (const float*)d_in[3];  // (128,)
    const float* u     = (const float*)d_in[4];  // (256,)
    float* out = (float*)d_out;                  // (32, 8192)

    gat_fused<<<BATCH / B_TILE, 256, 0, stream>>>(ai_sq, ai_sn, W_w, W_b, u, out);
}